// Round 1
// baseline (143.372 us; speedup 1.0000x reference)
//
#include <hip/hip_runtime.h>

#define NPTS 8192
#define BATCH 4
#define JT 512          // refs per LDS tile (one tile per block)
#define QPT 4           // queries per thread
#define IT (256 * QPT)  // queries per block = 1024

constexpr float SENT_N  = 1e9f;   // sentinel norm for masked-out points
constexpr float INITMIN = 1e30f;  // init value for min buffers (positive -> uint-orderable)

// ws layout:
//   cleanQ : BATCH*NPTS float4   (x,y,z,|.|^2), masked -> (0,0,0,SENT_N)
//   predQ  : BATCH*NPTS float4
//   min0   : BATCH*NPTS float    row-mins dir 0 (query=clean, ref=pred)
//   min1   : BATCH*NPTS float    row-mins dir 1 (query=pred, ref=clean)

__global__ __launch_bounds__(256) void prep_kernel(
    const float* __restrict__ pred, const float* __restrict__ target,
    const int* __restrict__ mask, const float* __restrict__ points,
    float4* __restrict__ cleanQ, float4* __restrict__ predQ,
    float* __restrict__ min0, float* __restrict__ min1,
    float* __restrict__ out) {
  int g = blockIdx.x * blockDim.x + threadIdx.x;
  if (g == 0) out[0] = 0.0f;  // accumulators start at zero (d_out is poisoned)
  if (g >= BATCH * NPTS) return;
  int m = mask[g];
  float px = pred[3 * g], py = pred[3 * g + 1], pz = pred[3 * g + 2];
  float tx = target[3 * g], ty = target[3 * g + 1], tz = target[3 * g + 2];
  float ox = points[3 * g], oy = points[3 * g + 1], oz = points[3 * g + 2];
  float cx = ox + tx, cy = oy + ty, cz = oz + tz;   // clean
  float qx = ox + px, qy = oy + py, qz = oz + pz;   // predicted denoised
  if (m) {
    cleanQ[g] = make_float4(cx, cy, cz, cx * cx + cy * cy + cz * cz);
    predQ[g]  = make_float4(qx, qy, qz, qx * qx + qy * qy + qz * qz);
  } else {
    // sentinel: huge norm, zero coords -> distance to anything ~1e9, never wins min
    cleanQ[g] = make_float4(0.f, 0.f, 0.f, SENT_N);
    predQ[g]  = make_float4(0.f, 0.f, 0.f, SENT_N);
  }
  min0[g] = INITMIN;
  min1[g] = INITMIN;
}

// One block handles: batch b, direction dir, IT queries x JT refs.
// d2 = |q|^2 + |r|^2 - 2 q.r ; refs staged in LDS pre-scaled to (-2x,-2y,-2z,|r|^2)
// so the pair kernel is: t = qn + rw; t = fma(qx,rx,t); fma(qy,ry,t); fma(qz,rz,t); min.
__global__ __launch_bounds__(256) void chamfer_kernel(
    const float4* __restrict__ cleanQ, const float4* __restrict__ predQ,
    float* __restrict__ min0, float* __restrict__ min1) {
  __shared__ float4 tile[JT];
  int z = blockIdx.z;  // dir*4 + b
  int dir = z >> 2;
  int b = z & 3;
  const float4* __restrict__ q = dir ? predQ : cleanQ;
  const float4* __restrict__ r = dir ? cleanQ : predQ;
  float* __restrict__ outmin = dir ? min1 : min0;

  int jbase = blockIdx.x * JT;
  int ibase = blockIdx.y * IT;
  int t = threadIdx.x;

  // stage ref tile into LDS (coalesced float4 loads), pre-scale by -2
  for (int k = t; k < JT; k += 256) {
    float4 v = r[b * NPTS + jbase + k];
    tile[k] = make_float4(-2.f * v.x, -2.f * v.y, -2.f * v.z, v.w);
  }
  __syncthreads();

  float4 qv[QPT];
  float vmin[QPT];
  int idx0 = b * NPTS + ibase + t;
#pragma unroll
  for (int k = 0; k < QPT; k++) {
    qv[k] = q[idx0 + k * 256];
    vmin[k] = INITMIN;
  }

#pragma unroll 4
  for (int j = 0; j < JT; j++) {
    float4 rv = tile[j];  // same address across the wave -> LDS broadcast, no conflicts
#pragma unroll
    for (int k = 0; k < QPT; k++) {
      float tt = qv[k].w + rv.w;
      tt = fmaf(qv[k].x, rv.x, tt);
      tt = fmaf(qv[k].y, rv.y, tt);
      tt = fmaf(qv[k].z, rv.z, tt);
      vmin[k] = fminf(vmin[k], tt);
    }
  }

#pragma unroll
  for (int k = 0; k < QPT; k++) {
    // relu commutes with min; clamp so all atomic values are >= 0 -> uint order == float order
    float v = fmaxf(vmin[k], 0.f);
    atomicMin((unsigned int*)&outmin[idx0 + k * 256], __float_as_uint(v));
  }
}

// blocks 0..7: (dir,b) masked sum of mins + per-batch mask count; block 8: L1 term.
__global__ __launch_bounds__(256) void finalsum_kernel(
    const float* __restrict__ pred, const float* __restrict__ target,
    const int* __restrict__ mask,
    const float* __restrict__ min0, const float* __restrict__ min1,
    float* __restrict__ out) {
  int bid = blockIdx.x;
  int t = threadIdx.x;
  __shared__ float red0[4], red1[4];
  float s0 = 0.f, s1 = 0.f;
  if (bid < 8) {
    int dir = bid >> 2, b = bid & 3;
    const float* __restrict__ mn = dir ? min1 : min0;
    for (int i = t; i < NPTS; i += 256) {
      float m = (float)mask[b * NPTS + i];
      s0 += m * mn[b * NPTS + i];
      s1 += m;
    }
  } else {
    for (int g = t; g < BATCH * NPTS; g += 256) {
      float m = (float)mask[g];
      float d0 = fabsf(pred[3 * g] - target[3 * g]);
      float d1 = fabsf(pred[3 * g + 1] - target[3 * g + 1]);
      float d2 = fabsf(pred[3 * g + 2] - target[3 * g + 2]);
      s0 += m * (d0 + d1 + d2) * (1.f / 3.f);
      s1 += m;
    }
  }
  // wave64 butterfly then cross-wave via LDS
  for (int off = 32; off; off >>= 1) {
    s0 += __shfl_down(s0, off);
    s1 += __shfl_down(s1, off);
  }
  int wave = t >> 6;
  if ((t & 63) == 0) { red0[wave] = s0; red1[wave] = s1; }
  __syncthreads();
  if (t == 0) {
    s0 = red0[0] + red0[1] + red0[2] + red0[3];
    s1 = red1[0] + red1[1] + red1[2] + red1[3];
    if (bid < 8) {
      // 0.5 * (masked min sum / count_b) / B
      atomicAdd(out, 0.5f * s0 / fmaxf(s1, 1.f) * (1.f / BATCH));
    } else {
      // 0.5 * l1_masked_mean
      atomicAdd(out, 0.5f * s0 / s1);
    }
  }
}

extern "C" void kernel_launch(void* const* d_in, const int* in_sizes, int n_in,
                              void* d_out, int out_size, void* d_ws, size_t ws_size,
                              hipStream_t stream) {
  const float* pred   = (const float*)d_in[0];
  const float* target = (const float*)d_in[1];
  const int*   mask   = (const int*)d_in[2];
  const float* points = (const float*)d_in[3];
  float* out = (float*)d_out;

  float4* cleanQ = (float4*)d_ws;
  float4* predQ  = cleanQ + BATCH * NPTS;
  float*  min0   = (float*)(predQ + BATCH * NPTS);
  float*  min1   = min0 + BATCH * NPTS;

  prep_kernel<<<(BATCH * NPTS) / 256, 256, 0, stream>>>(
      pred, target, mask, points, cleanQ, predQ, min0, min1, out);

  dim3 grid(NPTS / JT, NPTS / IT, 2 * BATCH);  // (16, 8, 8) = 1024 blocks
  chamfer_kernel<<<grid, 256, 0, stream>>>(cleanQ, predQ, min0, min1);

  finalsum_kernel<<<9, 256, 0, stream>>>(pred, target, mask, min0, min1, out);
}

// Round 2
// 123.267 us; speedup vs baseline: 1.1631x; 1.1631x over previous
//
#include <hip/hip_runtime.h>

#define NPTS 8192
#define BATCH 4
#define JT 512          // refs per LDS tile
#define QPT 8           // queries per thread
#define IT (256 * QPT)  // queries per block = 2048

constexpr float SENT_N  = 1e9f;   // sentinel norm for masked-out points
constexpr float INITMIN = 1e30f;  // init for min buffers (positive -> uint order == float order)

// Accumulators living at the end of ws (zeroed via hipMemsetAsync before prep)
struct Accum {
  float l1sum;         // sum of m * mean_d |pred-target|
  float count[BATCH];  // per-batch mask count
  float minsum[8];     // [dir*4+b] masked sum of row mins
  float pad[3];
};

// ws layout:
//   cleanQ : BATCH*NPTS float4 (x,y,z,|.|^2), masked -> (0,0,0,SENT_N)
//   predQ  : BATCH*NPTS float4
//   min0   : BATCH*NPTS float   (query=clean, ref=pred)
//   min1   : BATCH*NPTS float   (query=pred, ref=clean)
//   Accum

__global__ __launch_bounds__(256) void prep_kernel(
    const float* __restrict__ pred, const float* __restrict__ target,
    const int* __restrict__ mask, const float* __restrict__ points,
    float4* __restrict__ cleanQ, float4* __restrict__ predQ,
    float* __restrict__ min0, float* __restrict__ min1,
    Accum* __restrict__ acc) {
  int g = blockIdx.x * 256 + threadIdx.x;   // exactly BATCH*NPTS threads
  int b = g >> 13;                          // g / NPTS; blocks never straddle batches
  int m = mask[g];
  float fm = (float)m;
  float px = pred[3 * g], py = pred[3 * g + 1], pz = pred[3 * g + 2];
  float tx = target[3 * g], ty = target[3 * g + 1], tz = target[3 * g + 2];
  float ox = points[3 * g], oy = points[3 * g + 1], oz = points[3 * g + 2];

  // L1 contribution (masked)
  float l1c = fm * (fabsf(px - tx) + fabsf(py - ty) + fabsf(pz - tz)) * (1.f / 3.f);

  float cx = ox + tx, cy = oy + ty, cz = oz + tz;   // clean
  float qx = ox + px, qy = oy + py, qz = oz + pz;   // predicted denoised
  if (m) {
    cleanQ[g] = make_float4(cx, cy, cz, cx * cx + cy * cy + cz * cz);
    predQ[g]  = make_float4(qx, qy, qz, qx * qx + qy * qy + qz * qz);
  } else {
    cleanQ[g] = make_float4(0.f, 0.f, 0.f, SENT_N);
    predQ[g]  = make_float4(0.f, 0.f, 0.f, SENT_N);
  }
  min0[g] = INITMIN;
  min1[g] = INITMIN;

  // wave64 reduce l1c and fm, one atomic per wave
  for (int off = 32; off; off >>= 1) {
    l1c += __shfl_down(l1c, off);
    fm  += __shfl_down(fm, off);
  }
  if ((threadIdx.x & 63) == 0) {
    atomicAdd(&acc->l1sum, l1c);
    atomicAdd(&acc->count[b], fm);
  }
}

// d2 = |q|^2 + |r|^2 - 2 q.r. Refs staged in LDS as (-2x,-2y,-2z,|r|^2).
// Track vmin' = min_j (rn - 2 q.r)  [fma chain seeded with rv.w]; add |q|^2 once
// in the epilogue (min commutes with a constant shift). Refs processed in pairs
// so fminf(fminf(t0,t1),vmin) folds to v_min3_f32 -> 3.5 VALU ops per pair.
__global__ __launch_bounds__(256) void chamfer_kernel(
    const float4* __restrict__ cleanQ, const float4* __restrict__ predQ,
    float* __restrict__ min0, float* __restrict__ min1) {
  __shared__ float4 tile[JT];
  int z = blockIdx.z;  // dir*4 + b
  int dir = z >> 2;
  int b = z & 3;
  const float4* __restrict__ q = dir ? predQ : cleanQ;
  const float4* __restrict__ r = dir ? cleanQ : predQ;
  float* __restrict__ outmin = dir ? min1 : min0;

  int jbase = blockIdx.x * JT;
  int ibase = blockIdx.y * IT;
  int t = threadIdx.x;

  for (int k = t; k < JT; k += 256) {
    float4 v = r[b * NPTS + jbase + k];
    tile[k] = make_float4(-2.f * v.x, -2.f * v.y, -2.f * v.z, v.w);
  }
  __syncthreads();

  float4 qv[QPT];
  float vmin[QPT];
  int idx0 = b * NPTS + ibase + t;
#pragma unroll
  for (int k = 0; k < QPT; k++) {
    qv[k] = q[idx0 + k * 256];
    vmin[k] = INITMIN;
  }

#pragma unroll 4
  for (int j = 0; j < JT; j += 2) {
    float4 r0 = tile[j];
    float4 r1 = tile[j + 1];
#pragma unroll
    for (int k = 0; k < QPT; k++) {
      float t0 = fmaf(qv[k].x, r0.x, r0.w);
      t0 = fmaf(qv[k].y, r0.y, t0);
      t0 = fmaf(qv[k].z, r0.z, t0);
      float t1 = fmaf(qv[k].x, r1.x, r1.w);
      t1 = fmaf(qv[k].y, r1.y, t1);
      t1 = fmaf(qv[k].z, r1.z, t1);
      vmin[k] = fminf(fminf(t0, t1), vmin[k]);   // -> v_min3_f32
    }
  }

#pragma unroll
  for (int k = 0; k < QPT; k++) {
    // add back |q|^2; relu commutes with min; clamp >=0 so uint order == float order
    float v = fmaxf(vmin[k] + qv[k].w, 0.f);
    atomicMin((unsigned int*)&outmin[idx0 + k * 256], __float_as_uint(v));
  }
}

// 64 blocks: 8 blocks per (dir,b) slice, each reduces 1024 mins (masked), atomicAdd partial.
__global__ __launch_bounds__(256) void minreduce_kernel(
    const int* __restrict__ mask,
    const float* __restrict__ min0, const float* __restrict__ min1,
    Accum* __restrict__ acc) {
  int slice = blockIdx.x >> 3;  // 0..7 = dir*4+b
  int sub = blockIdx.x & 7;
  int dir = slice >> 2, b = slice & 3;
  const float* __restrict__ mn = dir ? min1 : min0;
  int base = b * NPTS + sub * 1024;
  int t = threadIdx.x;

  const float4* mn4 = (const float4*)(mn + base);
  const int4* mk4 = (const int4*)(mask + b * NPTS + sub * 1024);
  float4 v = mn4[t];
  int4 mm = mk4[t];
  float s = (float)mm.x * v.x + (float)mm.y * v.y + (float)mm.z * v.z + (float)mm.w * v.w;

  for (int off = 32; off; off >>= 1) s += __shfl_down(s, off);
  __shared__ float red[4];
  int wave = t >> 6;
  if ((t & 63) == 0) red[wave] = s;
  __syncthreads();
  if (t == 0) atomicAdd(&acc->minsum[slice], red[0] + red[1] + red[2] + red[3]);
}

__global__ void final_kernel(const Accum* __restrict__ acc, float* __restrict__ out) {
  if (threadIdx.x == 0) {
    float msum = 0.f, cham = 0.f;
#pragma unroll
    for (int b = 0; b < BATCH; b++) {
      msum += acc->count[b];
      cham += (acc->minsum[b] + acc->minsum[4 + b]) / fmaxf(acc->count[b], 1.f);
    }
    out[0] = 0.5f * (acc->l1sum / msum + cham * (1.f / BATCH));
  }
}

extern "C" void kernel_launch(void* const* d_in, const int* in_sizes, int n_in,
                              void* d_out, int out_size, void* d_ws, size_t ws_size,
                              hipStream_t stream) {
  const float* pred   = (const float*)d_in[0];
  const float* target = (const float*)d_in[1];
  const int*   mask   = (const int*)d_in[2];
  const float* points = (const float*)d_in[3];
  float* out = (float*)d_out;

  float4* cleanQ = (float4*)d_ws;
  float4* predQ  = cleanQ + BATCH * NPTS;
  float*  min0   = (float*)(predQ + BATCH * NPTS);
  float*  min1   = min0 + BATCH * NPTS;
  Accum*  acc    = (Accum*)(min1 + BATCH * NPTS);

  hipMemsetAsync(acc, 0, sizeof(Accum), stream);

  prep_kernel<<<(BATCH * NPTS) / 256, 256, 0, stream>>>(
      pred, target, mask, points, cleanQ, predQ, min0, min1, acc);

  dim3 grid(NPTS / JT, NPTS / IT, 2 * BATCH);  // (16, 4, 8) = 512 blocks
  chamfer_kernel<<<grid, 256, 0, stream>>>(cleanQ, predQ, min0, min1);

  minreduce_kernel<<<64, 256, 0, stream>>>(mask, min0, min1, acc);
  final_kernel<<<1, 64, 0, stream>>>(acc, out);
}

// Round 3
// 115.518 us; speedup vs baseline: 1.2411x; 1.0671x over previous
//
#include <hip/hip_runtime.h>

#define NPTS 8192
#define BATCH 4
#define CHUNK 512   // queries per block == refs per block

typedef __attribute__((ext_vector_type(8))) short bf16x8;   // 8 bf16 = 4 VGPRs
typedef __attribute__((ext_vector_type(16))) float f32x16;  // 32x32 MFMA acc

struct Accum {
  float l1sum;
  float count[BATCH];
  float minsum[8];  // [dir*4+b]
  float pad[3];
};

__device__ __forceinline__ unsigned short f2bf(float x) {  // RNE fp32->bf16
  union { float f; unsigned u; } v; v.f = x;
  unsigned r = v.u + 0x7FFFu + ((v.u >> 16) & 1u);
  return (unsigned short)(r >> 16);
}
__device__ __forceinline__ float bf2f(unsigned short h) {
  union { float f; unsigned u; } v; v.u = ((unsigned)h) << 16;
  return v.f;
}

// d2[q][r] = qn + rn - 2 q.r  (+1e9 if ref masked). MFMA computes rn' - 2 q.r via
// K=16 bf16 slots: per coord c: A=[yh,yh,yl,yl] B=[rh,rl,rh,rl] (y = -2q, hi/lo split);
// slots 12-14: A=[1,1,1], B = 3-way bf16 split of rn' -> exact to ~4e-7. Slot 15 zero.
// qn added in fp32 epilogue (min commutes with per-row constant). Any uniform HW
// K-permutation is harmless: A and B use identical k-indexing.
__global__ __launch_bounds__(256, 3) void chamfer_kernel(
    const float* __restrict__ pred, const float* __restrict__ target,
    const int* __restrict__ mask, const float* __restrict__ points,
    unsigned int* __restrict__ min0, unsigned int* __restrict__ min1) {
  __shared__ __align__(16) unsigned short Apack[CHUNK * 16];
  __shared__ __align__(16) unsigned short Bpack[CHUNK * 16];
  __shared__ float qnS[CHUNK];

  int z = blockIdx.z, dir = z >> 2, b = z & 3;
  const float* __restrict__ dq = dir ? pred : target;   // query = pred-denoised if dir1 else clean
  const float* __restrict__ dr = dir ? target : pred;   // ref   = the other one
  unsigned int* __restrict__ outmin = dir ? min1 : min0;

  int jbase = blockIdx.x * CHUNK;
  int qbase = blockIdx.y * CHUNK;
  int tid = threadIdx.x;
  const unsigned short ONE = 0x3F80;  // bf16 1.0

  // ---- fused staging: build A/B packs from raw inputs (2 points per thread/side)
  for (int i = tid; i < CHUNK; i += 256) {
    {  // query side -> Apack + qn
      int g = b * NPTS + qbase + i;
      float qx = points[3 * g] + dq[3 * g];
      float qy = points[3 * g + 1] + dq[3 * g + 1];
      float qz = points[3 * g + 2] + dq[3 * g + 2];
      qnS[i] = qx * qx + qy * qy + qz * qz;
      float yx = -2.f * qx, yy = -2.f * qy, yz = -2.f * qz;
      unsigned short xh = f2bf(yx), xl = f2bf(yx - bf2f(xh));
      unsigned short yh = f2bf(yy), yl = f2bf(yy - bf2f(yh));
      unsigned short zh = f2bf(yz), zl = f2bf(yz - bf2f(zh));
      uint4 v0, v1;
      v0.x = (unsigned)xh | ((unsigned)xh << 16);
      v0.y = (unsigned)xl | ((unsigned)xl << 16);
      v0.z = (unsigned)yh | ((unsigned)yh << 16);
      v0.w = (unsigned)yl | ((unsigned)yl << 16);
      v1.x = (unsigned)zh | ((unsigned)zh << 16);
      v1.y = (unsigned)zl | ((unsigned)zl << 16);
      v1.z = (unsigned)ONE | ((unsigned)ONE << 16);
      v1.w = (unsigned)ONE;  // slot14=1, slot15=0
      uint4* dst = (uint4*)&Apack[i * 16];
      dst[0] = v0; dst[1] = v1;
    }
    {  // ref side -> Bpack (rn' includes +1e9 mask penalty; coords stay real)
      int g = b * NPTS + jbase + i;
      float rx = points[3 * g] + dr[3 * g];
      float ry = points[3 * g + 1] + dr[3 * g + 1];
      float rz = points[3 * g + 2] + dr[3 * g + 2];
      float rn = rx * rx + ry * ry + rz * rz + (mask[g] ? 0.f : 1e9f);
      unsigned short xh = f2bf(rx), xl = f2bf(rx - bf2f(xh));
      unsigned short yh = f2bf(ry), yl = f2bf(ry - bf2f(yh));
      unsigned short zh = f2bf(rz), zl = f2bf(rz - bf2f(zh));
      unsigned short nh = f2bf(rn);
      float rem = rn - bf2f(nh);
      unsigned short nm = f2bf(rem);
      unsigned short nl = f2bf(rem - bf2f(nm));
      uint4 v0, v1;
      v0.x = (unsigned)xh | ((unsigned)xl << 16);
      v0.y = v0.x;
      v0.z = (unsigned)yh | ((unsigned)yl << 16);
      v0.w = v0.z;
      v1.x = (unsigned)zh | ((unsigned)zl << 16);
      v1.y = v1.x;
      v1.z = (unsigned)nh | ((unsigned)nm << 16);
      v1.w = (unsigned)nl;  // slot15=0
      uint4* dst = (uint4*)&Bpack[i * 16];
      dst[0] = v0; dst[1] = v1;
    }
  }
  __syncthreads();

  int lane = tid & 63, w = tid >> 6;
  int n = lane & 31, h = lane >> 5;  // A: m=lane&31, k-chunk=lane>>5 ; B mirrored

  const bf16x8* Ab = (const bf16x8*)Apack;
  const bf16x8* Bb = (const bf16x8*)Bpack;
  bf16x8 afr[4];
#pragma unroll
  for (int q = 0; q < 4; q++) {
    int qt = w * 4 + q;  // wave owns 4 query-tiles of 32
    afr[q] = Ab[(qt * 32 + n) * 2 + h];
  }
  f32x16 vmin[4];
#pragma unroll
  for (int q = 0; q < 4; q++)
#pragma unroll
    for (int r = 0; r < 16; r++) vmin[q][r] = 1e30f;

  f32x16 zero = {0.f, 0.f, 0.f, 0.f, 0.f, 0.f, 0.f, 0.f,
                 0.f, 0.f, 0.f, 0.f, 0.f, 0.f, 0.f, 0.f};

  for (int p = 0; p < 8; p++) {  // 16 ref-tiles of 32, in pairs for min3 folding
    bf16x8 bf0 = Bb[((p * 2) * 32 + n) * 2 + h];
    bf16x8 bf1 = Bb[((p * 2 + 1) * 32 + n) * 2 + h];
#pragma unroll
    for (int q = 0; q < 4; q++) {
      f32x16 d0 = __builtin_amdgcn_mfma_f32_32x32x16_bf16(afr[q], bf0, zero, 0, 0, 0);
      f32x16 d1 = __builtin_amdgcn_mfma_f32_32x32x16_bf16(afr[q], bf1, zero, 0, 0, 0);
#pragma unroll
      for (int r = 0; r < 16; r++)
        vmin[q][r] = fminf(fminf(d0[r], d1[r]), vmin[q][r]);
    }
  }

  // ---- epilogue: min across the 32 cols (refs) per row, add qn, relu, atomicMin
#pragma unroll
  for (int q = 0; q < 4; q++) {
    int qt = w * 4 + q;
#pragma unroll
    for (int r = 0; r < 16; r++) {
      float v = vmin[q][r];
      v = fminf(v, __shfl_xor(v, 1));
      v = fminf(v, __shfl_xor(v, 2));
      v = fminf(v, __shfl_xor(v, 4));
      v = fminf(v, __shfl_xor(v, 8));
      v = fminf(v, __shfl_xor(v, 16));
      vmin[q][r] = v;  // xor<32 stays within each 32-lane half
    }
    if (n == 0) {  // lanes 0 and 32: each half owns 16 distinct rows
#pragma unroll
      for (int r = 0; r < 16; r++) {
        int row = (r & 3) + 8 * (r >> 2) + 4 * h;  // C/D layout (m74/m101)
        int li = qt * 32 + row;
        float v = fmaxf(vmin[q][r] + qnS[li], 0.f);
        atomicMin(&outmin[b * NPTS + qbase + li], __float_as_uint(v));
      }
    }
  }
}

// 64 blocks: 8 per (dir,b) slice; masked min-sum; dir0 blocks also do count + L1.
__global__ __launch_bounds__(256) void reduce_kernel(
    const float* __restrict__ pred, const float* __restrict__ target,
    const int* __restrict__ mask,
    const unsigned int* __restrict__ min0, const unsigned int* __restrict__ min1,
    Accum* __restrict__ acc) {
  int slice = blockIdx.x >> 3, sub = blockIdx.x & 7;
  int dir = slice >> 2, bb = slice & 3;
  const float* __restrict__ mn = (const float*)(dir ? min1 : min0);
  int base = bb * NPTS + sub * 1024;
  int t = threadIdx.x;

  const float4* mn4 = (const float4*)(mn + base);
  const int4* mk4 = (const int4*)(mask + base);
  float4 v = mn4[t];
  int4 mm = mk4[t];
  float s = mm.x * v.x + mm.y * v.y + mm.z * v.z + mm.w * v.w;
  float c = (float)(mm.x + mm.y + mm.z + mm.w);
  float l1 = 0.f;
  if (dir == 0) {
    for (int i = t; i < 1024; i += 256) {
      int g = base + i;
      float m = (float)mask[g];
      l1 += m * (fabsf(pred[3 * g] - target[3 * g]) +
                 fabsf(pred[3 * g + 1] - target[3 * g + 1]) +
                 fabsf(pred[3 * g + 2] - target[3 * g + 2])) * (1.f / 3.f);
    }
  }
  for (int off = 32; off; off >>= 1) {
    s += __shfl_down(s, off);
    c += __shfl_down(c, off);
    l1 += __shfl_down(l1, off);
  }
  __shared__ float rs[4], rc[4], rl[4];
  int wave = t >> 6;
  if ((t & 63) == 0) { rs[wave] = s; rc[wave] = c; rl[wave] = l1; }
  __syncthreads();
  if (t == 0) {
    atomicAdd(&acc->minsum[slice], rs[0] + rs[1] + rs[2] + rs[3]);
    if (dir == 0) {
      atomicAdd(&acc->count[bb], rc[0] + rc[1] + rc[2] + rc[3]);
      atomicAdd(&acc->l1sum, rl[0] + rl[1] + rl[2] + rl[3]);
    }
  }
}

__global__ void final_kernel(const Accum* __restrict__ acc, float* __restrict__ out) {
  if (threadIdx.x == 0) {
    float msum = 0.f, cham = 0.f;
#pragma unroll
    for (int b = 0; b < BATCH; b++) {
      msum += acc->count[b];
      cham += (acc->minsum[b] + acc->minsum[4 + b]) / fmaxf(acc->count[b], 1.f);
    }
    out[0] = 0.5f * (acc->l1sum / msum + cham * (1.f / BATCH));
  }
}

extern "C" void kernel_launch(void* const* d_in, const int* in_sizes, int n_in,
                              void* d_out, int out_size, void* d_ws, size_t ws_size,
                              hipStream_t stream) {
  const float* pred   = (const float*)d_in[0];
  const float* target = (const float*)d_in[1];
  const int*   mask   = (const int*)d_in[2];
  const float* points = (const float*)d_in[3];
  float* out = (float*)d_out;

  unsigned int* min0 = (unsigned int*)d_ws;
  unsigned int* min1 = min0 + BATCH * NPTS;
  Accum* acc = (Accum*)(min1 + BATCH * NPTS);

  // 0x7F7F7F7F == 3.396e38f: valid huge positive float, uint order == float order
  hipMemsetAsync(min0, 0x7F, 2 * BATCH * NPTS * sizeof(unsigned int), stream);
  hipMemsetAsync(acc, 0, sizeof(Accum), stream);

  dim3 grid(NPTS / CHUNK, NPTS / CHUNK, 2 * BATCH);  // (16, 16, 8) = 2048 blocks
  chamfer_kernel<<<grid, 256, 0, stream>>>(pred, target, mask, points, min0, min1);

  reduce_kernel<<<64, 256, 0, stream>>>(pred, target, mask, min0, min1, acc);
  final_kernel<<<1, 64, 0, stream>>>(acc, out);
}